// Round 1
// baseline (634.162 us; speedup 1.0000x reference)
//
#include <hip/hip_runtime.h>

#define BLOCK 256
#define TE 64   // edges per tile
#define TN 64   // nodes per tile

// ---------------------------------------------------------------------------
// Kernel 1: per-edge MLP + gather x[src] + atomic scatter-add into agg[dst]
//   h = relu(ea @ W1^T + b1)          [E,96]
//   w = h @ W2^T + b2                 [E,96]
//   agg[dst] += w * x[src]
// Persistent grid; weights staged in LDS once per block. 8e x 3d micro-tile.
// LDS ~75.5KB -> 2 blocks/CU.
// ---------------------------------------------------------------------------
__global__ __launch_bounds__(BLOCK, 2) void edge_kernel(
    const float* __restrict__ x,     // [N][96]
    const int*   __restrict__ ei,    // [2][E]
    const float* __restrict__ ea,    // [E][17]
    const float* __restrict__ W1,    // [96][17]
    const float* __restrict__ b1,    // [96]
    const float* __restrict__ W2,    // [96][96]
    const float* __restrict__ b2,    // [96]
    float* __restrict__ agg,         // [N][96]
    int N, int E)
{
    __shared__ float sW1[96][18];
    __shared__ float sW2[96][98];   // pad 98: rows 8B-aligned, 2-way conflicts only (free)
    __shared__ float sb1[96], sb2[96];
    __shared__ float sea[TE][18];
    __shared__ float sh[TE][98];
    __shared__ int   ssrc[TE], sdst[TE];

    const int tid = threadIdx.x;

    // stage weights once per block
    for (int idx = tid; idx < 96 * 17; idx += BLOCK) sW1[idx / 17][idx % 17] = W1[idx];
    for (int idx = tid; idx < 96 * 96; idx += BLOCK) sW2[idx / 96][idx % 96] = W2[idx];
    if (tid < 96) { sb1[tid] = b1[tid]; sb2[tid] = b2[tid]; }

    const int c  = tid & 31;   // d-lane: d in {c, c+32, c+64}
    const int eg = tid >> 5;   // edge group 0..7: edges eg*8 .. eg*8+7

    const int ntiles = (E + TE - 1) / TE;
    for (int tile = blockIdx.x; tile < ntiles; tile += gridDim.x) {
        const int e0 = tile * TE;
        __syncthreads();  // protect LDS (prev iter reads / initial weight stage)

        // stage edge_attr tile (contiguous -> coalesced) + indices
        for (int idx = tid; idx < TE * 17; idx += BLOCK) {
            int e = idx / 17, k = idx - e * 17;
            float v = 0.f;
            if (e0 + e < E) v = ea[(size_t)(e0 + e) * 17 + k];
            sea[e][k] = v;
        }
        if (tid < TE) {
            int e = e0 + tid;
            ssrc[tid] = (e < E) ? ei[e] : 0;
            sdst[tid] = (e < E) ? ei[E + e] : 0;
        }
        __syncthreads();

        // h = relu(ea @ W1^T + b1): TE*96 outputs, 24 per thread
        #pragma unroll
        for (int j = 0; j < TE * 96 / BLOCK; ++j) {
            int idx = tid + j * BLOCK;
            int e = idx / 96, d = idx - e * 96;
            float acc = sb1[d];
            #pragma unroll
            for (int k = 0; k < 17; ++k) acc += sea[e][k] * sW1[d][k];
            sh[e][d] = fmaxf(acc, 0.f);
        }
        __syncthreads();

        // w = h @ W2^T + b2 with 8x3 register micro-tile, then gather/scatter
        float acc[8][3];
        #pragma unroll
        for (int i = 0; i < 8; ++i) {
            float bb0 = sb2[c], bb1 = sb2[c + 32], bb2v = sb2[c + 64];
            acc[i][0] = bb0; acc[i][1] = bb1; acc[i][2] = bb2v;
        }
        #pragma unroll 4
        for (int k = 0; k < 96; ++k) {
            float wv0 = sW2[c][k], wv1 = sW2[c + 32][k], wv2 = sW2[c + 64][k];
            #pragma unroll
            for (int i = 0; i < 8; ++i) {
                float hv = sh[eg * 8 + i][k];
                acc[i][0] += hv * wv0;
                acc[i][1] += hv * wv1;
                acc[i][2] += hv * wv2;
            }
        }
        #pragma unroll
        for (int i = 0; i < 8; ++i) {
            int el = eg * 8 + i;
            int e  = e0 + el;
            if (e < E) {
                int s = ssrc[el], dn = sdst[el];
                const float* __restrict__ xr = x + (size_t)s * 96;
                float* __restrict__ ar = agg + (size_t)dn * 96;
                #pragma unroll
                for (int j = 0; j < 3; ++j) {
                    int d = c + 32 * j;
                    atomicAdd(&ar[d], acc[i][j] * xr[d]);
                }
            }
        }
    }
}

// ---------------------------------------------------------------------------
// Kernel 2: out = relu(x @ Ws^T + bs + agg @ Wn^T + bn)
// Two K=96 phases sharing one LDS footprint (~63KB -> 2 blocks/CU).
// ---------------------------------------------------------------------------
__global__ __launch_bounds__(BLOCK, 2) void node_kernel(
    const float* __restrict__ x,
    const float* __restrict__ agg,
    const float* __restrict__ Ws, const float* __restrict__ bs,
    const float* __restrict__ Wn, const float* __restrict__ bn,
    float* __restrict__ out, int N)
{
    __shared__ float sW[96][98];
    __shared__ float sxa[TN][98];
    __shared__ float sbias[96];

    const int tid = threadIdx.x;
    const int c = tid & 31, ng = tid >> 5;
    const int n0 = blockIdx.x * TN;

    if (tid < 96) sbias[tid] = bs[tid] + bn[tid];

    float acc[8][3];
    #pragma unroll
    for (int i = 0; i < 8; ++i)
        for (int j = 0; j < 3; ++j) acc[i][j] = 0.f;

    for (int ph = 0; ph < 2; ++ph) {
        const float* __restrict__ W   = ph ? Wn : Ws;
        const float* __restrict__ src = ph ? agg : x;
        __syncthreads();  // protect prev phase LDS reads (and sbias stage)
        for (int idx = tid; idx < 96 * 96; idx += BLOCK) sW[idx / 96][idx % 96] = W[idx];
        for (int idx = tid; idx < TN * 96; idx += BLOCK) {
            int n = idx / 96, k = idx - n * 96;
            sxa[n][k] = (n0 + n < N) ? src[(size_t)(n0 + n) * 96 + k] : 0.f;
        }
        __syncthreads();
        #pragma unroll 4
        for (int k = 0; k < 96; ++k) {
            float wv0 = sW[c][k], wv1 = sW[c + 32][k], wv2 = sW[c + 64][k];
            #pragma unroll
            for (int i = 0; i < 8; ++i) {
                float xv = sxa[ng * 8 + i][k];
                acc[i][0] += xv * wv0;
                acc[i][1] += xv * wv1;
                acc[i][2] += xv * wv2;
            }
        }
    }

    #pragma unroll
    for (int i = 0; i < 8; ++i) {
        int n = n0 + ng * 8 + i;
        if (n < N) {
            #pragma unroll
            for (int j = 0; j < 3; ++j) {
                int d = c + 32 * j;
                out[(size_t)n * 96 + d] = fmaxf(acc[i][j] + sbias[d], 0.f);
            }
        }
    }
}

extern "C" void kernel_launch(void* const* d_in, const int* in_sizes, int n_in,
                              void* d_out, int out_size, void* d_ws, size_t ws_size,
                              hipStream_t stream) {
    const float* x  = (const float*)d_in[0];
    const int*   ei = (const int*)d_in[1];
    const float* ea = (const float*)d_in[2];
    const float* W1 = (const float*)d_in[3];
    const float* b1 = (const float*)d_in[4];
    const float* W2 = (const float*)d_in[5];
    const float* b2 = (const float*)d_in[6];
    const float* Ws = (const float*)d_in[7];
    const float* bs = (const float*)d_in[8];
    const float* Wn = (const float*)d_in[9];
    const float* bn = (const float*)d_in[10];
    float* out = (float*)d_out;

    const int N = in_sizes[0] / 96;
    const int E = in_sizes[2] / 17;

    // agg scratch: prefer workspace; d_out fallback is safe (node_kernel reads
    // its own 64 rows of agg into LDS before overwriting them).
    float* agg = (ws_size >= (size_t)N * 96 * sizeof(float)) ? (float*)d_ws : out;
    hipMemsetAsync(agg, 0, (size_t)N * 96 * sizeof(float), stream);

    edge_kernel<<<512, BLOCK, 0, stream>>>(x, ei, ea, W1, b1, W2, b2, agg, N, E);
    node_kernel<<<(N + TN - 1) / TN, BLOCK, 0, stream>>>(x, agg, Ws, bs, Wn, bn, out, N);
}

// Round 2
// 547.867 us; speedup vs baseline: 1.1575x; 1.1575x over previous
//
#include <hip/hip_runtime.h>

#define BLOCK 512
#define TE 64   // edges per tile
#define TN 64   // nodes per tile

// ---------------------------------------------------------------------------
// Kernel 1: per-edge MLP + gather x[src] + atomic scatter-add into agg[dst]
//   h = relu(ea @ W1^T + b1)          [E,96]
//   w = h @ W2^T + b2                 [E,96]
//   agg[dst] += w * x[src]
// 512 threads (16 groups x 32 lanes), 4 edges x 3 d per thread, k-unroll 4
// with float4 LDS reads. LDS ~76KB -> 2 blocks/CU = 16 waves/CU.
// ---------------------------------------------------------------------------
__global__ __launch_bounds__(BLOCK, 4) void edge_kernel(
    const float* __restrict__ x,     // [N][96]
    const int*   __restrict__ ei,    // [2][E]
    const float* __restrict__ ea,    // [E][17]
    const float* __restrict__ W1,    // [96][17]
    const float* __restrict__ b1,    // [96]
    const float* __restrict__ W2,    // [96][96]
    const float* __restrict__ b2,    // [96]
    float* __restrict__ agg,         // [N][96]
    int N, int E)
{
    __shared__ float sW1[96][20];    // k padded 17->20 (zero fill), 16B-aligned rows
    __shared__ float sW2[96][100];   // k padded 96->100, 16B-aligned rows
    __shared__ float sb1[96], sb2[96];
    __shared__ float sea[TE][20];
    __shared__ float sh[TE][100];
    __shared__ int   ssrc[TE], sdst[TE];

    const int tid = threadIdx.x;
    const int c   = tid & 31;   // d-lane: d in {c, c+32, c+64}
    const int g   = tid >> 5;   // group 0..15: edges g*4 .. g*4+3

    // stage weights once per block
    for (int idx = tid; idx < 96 * 20; idx += BLOCK) {
        int d = idx / 20, k = idx - d * 20;
        sW1[d][k] = (k < 17) ? W1[d * 17 + k] : 0.f;
    }
    for (int idx = tid; idx < 96 * 96; idx += BLOCK) {
        int d = idx / 96, k = idx - d * 96;
        sW2[d][k] = W2[idx];
    }
    if (tid < 96) { sb1[tid] = b1[tid]; sb2[tid] = b2[tid]; }

    const int ntiles = (E + TE - 1) / TE;
    for (int tile = blockIdx.x; tile < ntiles; tile += gridDim.x) {
        const int e0 = tile * TE;
        __syncthreads();  // prev-iter LDS reads / initial weight stage done

        // stage edge_attr tile (zero-padded cols 17..19) + indices
        for (int idx = tid; idx < TE * 20; idx += BLOCK) {
            int e = idx / 20, k = idx - e * 20;
            float v = 0.f;
            if (k < 17 && e0 + e < E) v = ea[(size_t)(e0 + e) * 17 + k];
            sea[e][k] = v;
        }
        if (tid < TE) {
            int e = e0 + tid;
            ssrc[tid] = (e < E) ? ei[e] : 0;
            sdst[tid] = (e < E) ? ei[E + e] : 0;
        }
        __syncthreads();

        // h = relu(ea @ W1^T + b1), 4x3 micro-tile, float4 over k
        {
            float acc[4][3];
            #pragma unroll
            for (int i = 0; i < 4; ++i) {
                acc[i][0] = sb1[c]; acc[i][1] = sb1[c + 32]; acc[i][2] = sb1[c + 64];
            }
            #pragma unroll
            for (int k0 = 0; k0 < 20; k0 += 4) {
                float4 w0 = *(const float4*)&sW1[c][k0];
                float4 w1 = *(const float4*)&sW1[c + 32][k0];
                float4 w2 = *(const float4*)&sW1[c + 64][k0];
                #pragma unroll
                for (int i = 0; i < 4; ++i) {
                    float4 av = *(const float4*)&sea[g * 4 + i][k0];
                    acc[i][0] += av.x * w0.x + av.y * w0.y + av.z * w0.z + av.w * w0.w;
                    acc[i][1] += av.x * w1.x + av.y * w1.y + av.z * w1.z + av.w * w1.w;
                    acc[i][2] += av.x * w2.x + av.y * w2.y + av.z * w2.z + av.w * w2.w;
                }
            }
            #pragma unroll
            for (int i = 0; i < 4; ++i) {
                sh[g * 4 + i][c]      = fmaxf(acc[i][0], 0.f);
                sh[g * 4 + i][c + 32] = fmaxf(acc[i][1], 0.f);
                sh[g * 4 + i][c + 64] = fmaxf(acc[i][2], 0.f);
            }
        }
        __syncthreads();

        // w = h @ W2^T + b2, 4x3 micro-tile, float4 over k
        float acc[4][3];
        #pragma unroll
        for (int i = 0; i < 4; ++i) {
            acc[i][0] = sb2[c]; acc[i][1] = sb2[c + 32]; acc[i][2] = sb2[c + 64];
        }
        #pragma unroll 2
        for (int k0 = 0; k0 < 96; k0 += 4) {
            float4 w0 = *(const float4*)&sW2[c][k0];
            float4 w1 = *(const float4*)&sW2[c + 32][k0];
            float4 w2 = *(const float4*)&sW2[c + 64][k0];
            #pragma unroll
            for (int i = 0; i < 4; ++i) {
                float4 hv = *(const float4*)&sh[g * 4 + i][k0];
                acc[i][0] += hv.x * w0.x + hv.y * w0.y + hv.z * w0.z + hv.w * w0.w;
                acc[i][1] += hv.x * w1.x + hv.y * w1.y + hv.z * w1.z + hv.w * w1.w;
                acc[i][2] += hv.x * w2.x + hv.y * w2.y + hv.z * w2.z + hv.w * w2.w;
            }
        }

        // gather x[src], scale, atomic scatter into agg[dst]
        #pragma unroll
        for (int i = 0; i < 4; ++i) {
            int el = g * 4 + i;
            int e  = e0 + el;
            if (e < E) {
                int s = ssrc[el], dn = sdst[el];
                const float* __restrict__ xr = x + (size_t)s * 96;
                float* __restrict__ ar = agg + (size_t)dn * 96;
                atomicAdd(&ar[c],      acc[i][0] * xr[c]);
                atomicAdd(&ar[c + 32], acc[i][1] * xr[c + 32]);
                atomicAdd(&ar[c + 64], acc[i][2] * xr[c + 64]);
            }
        }
    }
}

// ---------------------------------------------------------------------------
// Kernel 2: out = relu(x @ Ws^T + bs + agg @ Wn^T + bn)
// Same 4x3 micro-tile / float4 structure; 2 K=96 phases share LDS (~64KB).
// ---------------------------------------------------------------------------
__global__ __launch_bounds__(BLOCK, 4) void node_kernel(
    const float* __restrict__ x,
    const float* __restrict__ agg,
    const float* __restrict__ Ws, const float* __restrict__ bs,
    const float* __restrict__ Wn, const float* __restrict__ bn,
    float* __restrict__ out, int N)
{
    __shared__ float sW[96][100];
    __shared__ float sxa[TN][100];
    __shared__ float sbias[96];

    const int tid = threadIdx.x;
    const int c = tid & 31, g = tid >> 5;
    const int n0 = blockIdx.x * TN;

    if (tid < 96) sbias[tid] = bs[tid] + bn[tid];

    float acc[4][3];
    #pragma unroll
    for (int i = 0; i < 4; ++i)
        for (int j = 0; j < 3; ++j) acc[i][j] = 0.f;

    for (int ph = 0; ph < 2; ++ph) {
        const float* __restrict__ W   = ph ? Wn : Ws;
        const float* __restrict__ src = ph ? agg : x;
        __syncthreads();  // prev phase LDS reads done (and sbias staged)
        for (int idx = tid; idx < 96 * 24; idx += BLOCK) {
            int d = idx / 24, kq = idx - d * 24;
            *(float4*)&sW[d][kq * 4] = *(const float4*)&W[d * 96 + kq * 4];
        }
        for (int idx = tid; idx < TN * 24; idx += BLOCK) {
            int n = idx / 24, kq = idx - n * 24;
            float4 v = make_float4(0.f, 0.f, 0.f, 0.f);
            if (n0 + n < N) v = *(const float4*)&src[(size_t)(n0 + n) * 96 + kq * 4];
            *(float4*)&sxa[n][kq * 4] = v;
        }
        __syncthreads();
        #pragma unroll 2
        for (int k0 = 0; k0 < 96; k0 += 4) {
            float4 w0 = *(const float4*)&sW[c][k0];
            float4 w1 = *(const float4*)&sW[c + 32][k0];
            float4 w2 = *(const float4*)&sW[c + 64][k0];
            #pragma unroll
            for (int i = 0; i < 4; ++i) {
                float4 xv = *(const float4*)&sxa[g * 4 + i][k0];
                acc[i][0] += xv.x * w0.x + xv.y * w0.y + xv.z * w0.z + xv.w * w0.w;
                acc[i][1] += xv.x * w1.x + xv.y * w1.y + xv.z * w1.z + xv.w * w1.w;
                acc[i][2] += xv.x * w2.x + xv.y * w2.y + xv.z * w2.z + xv.w * w2.w;
            }
        }
    }

    #pragma unroll
    for (int i = 0; i < 4; ++i) {
        int n = n0 + g * 4 + i;
        if (n < N) {
            out[(size_t)n * 96 + c]      = fmaxf(acc[i][0] + sbias[c], 0.f);
            out[(size_t)n * 96 + c + 32] = fmaxf(acc[i][1] + sbias[c + 32], 0.f);
            out[(size_t)n * 96 + c + 64] = fmaxf(acc[i][2] + sbias[c + 64], 0.f);
        }
    }
}

extern "C" void kernel_launch(void* const* d_in, const int* in_sizes, int n_in,
                              void* d_out, int out_size, void* d_ws, size_t ws_size,
                              hipStream_t stream) {
    const float* x  = (const float*)d_in[0];
    const int*   ei = (const int*)d_in[1];
    const float* ea = (const float*)d_in[2];
    const float* W1 = (const float*)d_in[3];
    const float* b1 = (const float*)d_in[4];
    const float* W2 = (const float*)d_in[5];
    const float* b2 = (const float*)d_in[6];
    const float* Ws = (const float*)d_in[7];
    const float* bs = (const float*)d_in[8];
    const float* Wn = (const float*)d_in[9];
    const float* bn = (const float*)d_in[10];
    float* out = (float*)d_out;

    const int N = in_sizes[0] / 96;
    const int E = in_sizes[2] / 17;

    float* agg = (ws_size >= (size_t)N * 96 * sizeof(float)) ? (float*)d_ws : out;
    hipMemsetAsync(agg, 0, (size_t)N * 96 * sizeof(float), stream);

    edge_kernel<<<512, BLOCK, 0, stream>>>(x, ei, ea, W1, b1, W2, b2, agg, N, E);
    node_kernel<<<(N + TN - 1) / TN, BLOCK, 0, stream>>>(x, agg, Ws, bs, Wn, bn, out, N);
}

// Round 3
// 342.381 us; speedup vs baseline: 1.8522x; 1.6002x over previous
//
#include <hip/hip_runtime.h>

#define BLOCK 512
#define TE 64   // edges per tile
#define TN 64   // nodes per tile

typedef float f32x4 __attribute__((ext_vector_type(4)));
typedef short s16x8 __attribute__((ext_vector_type(8)));

static __device__ __forceinline__ unsigned short f2bf(float f) {
    unsigned int u = __float_as_uint(f);
    u += 0x7FFFu + ((u >> 16) & 1u);          // round-to-nearest-even
    return (unsigned short)(u >> 16);
}
static __device__ __forceinline__ float bf2f(unsigned short s) {
    return __uint_as_float(((unsigned int)s) << 16);
}

// ---------------------------------------------------------------------------
// Kernel 1: edge MLP + gather + atomic scatter.
//   h = relu(ea @ W1^T + b1)   : f32 VALU (K=17), emits bf16 hi/lo to LDS
//   w = h @ W2^T + b2          : MFMA 16x16x32 bf16, split-3 (hh + hl + lh)
//   agg[dst] += w * x[src]     : f32 gather + atomicAdd
// 8 waves: wave w -> m-row (w&3) of 4x16 edges, n-half (w>>2) of 3x16 dims.
// LDS ~80.3KB -> 2 blocks/CU.
// ---------------------------------------------------------------------------
__global__ __launch_bounds__(BLOCK, 4) void edge_kernel(
    const float* __restrict__ x,     // [N][96]
    const int*   __restrict__ ei,    // [2][E]
    const float* __restrict__ ea,    // [E][17]
    const float* __restrict__ W1,    // [96][17]
    const float* __restrict__ b1,    // [96]
    const float* __restrict__ W2,    // [96][96]
    const float* __restrict__ b2,    // [96]
    float* __restrict__ agg,         // [N][96]
    int N, int E)
{
    __shared__ unsigned short sW2h[96][104];  // bf16 hi, row pad 104 (bank stride 20 -> 2-way max)
    __shared__ unsigned short sW2l[96][104];  // bf16 lo
    __shared__ unsigned short sh_hi[TE][104];
    __shared__ unsigned short sh_lo[TE][104];
    __shared__ float sW1[96][20];
    __shared__ float sea[TE][20];
    __shared__ float sb1[96];
    __shared__ int   ssrc[TE], sdst[TE];

    const int tid  = threadIdx.x;
    const int c    = tid & 31;         // h-phase d-lane
    const int g    = tid >> 5;         // h-phase edge group
    const int lane = tid & 63;
    const int wv   = tid >> 6;         // wave 0..7
    const int mr   = wv & 3;           // m-row of 16 edges
    const int ng   = wv >> 2;          // n-half (0: d 0..47, 1: d 48..95)
    const int l15  = lane & 15;
    const int l4   = lane >> 4;

    // ---- stage weights once per block ----
    for (int idx = tid; idx < 96 * 20; idx += BLOCK) {
        int d = idx / 20, k = idx - d * 20;
        sW1[d][k] = (k < 17) ? W1[d * 17 + k] : 0.f;
    }
    for (int idx = tid; idx < 96 * 96; idx += BLOCK) {
        int d = idx / 96, k = idx - d * 96;
        float v = W2[idx];
        unsigned short hb = f2bf(v);
        sW2h[d][k] = hb;
        sW2l[d][k] = f2bf(v - bf2f(hb));
    }
    if (tid < 96) sb1[tid] = b1[tid];

    // per-lane b2 bias for this wave's 3 n-tiles
    float bias[3];
    #pragma unroll
    for (int t = 0; t < 3; ++t) bias[t] = b2[(ng * 3 + t) * 16 + l15];

    const int ntiles = (E + TE - 1) / TE;
    for (int tile = blockIdx.x; tile < ntiles; tile += gridDim.x) {
        const int e0 = tile * TE;
        __syncthreads();  // prev-iter LDS reads (ssrc/sh) done before restage

        // ---- stage edge_attr tile + indices ----
        for (int idx = tid; idx < TE * 20; idx += BLOCK) {
            int e = idx / 20, k = idx - e * 20;
            float v = 0.f;
            if (k < 17 && e0 + e < E) v = ea[(size_t)(e0 + e) * 17 + k];
            sea[e][k] = v;
        }
        if (tid < TE) {
            int e = e0 + tid;
            ssrc[tid] = (e < E) ? ei[e] : 0;
            sdst[tid] = (e < E) ? ei[E + e] : 0;
        }
        __syncthreads();

        // ---- h = relu(ea @ W1^T + b1) -> bf16 hi/lo ----
        {
            float hacc[4][3];
            #pragma unroll
            for (int i = 0; i < 4; ++i) {
                hacc[i][0] = sb1[c]; hacc[i][1] = sb1[c + 32]; hacc[i][2] = sb1[c + 64];
            }
            #pragma unroll
            for (int k0 = 0; k0 < 20; k0 += 4) {
                float4 w0 = *(const float4*)&sW1[c][k0];
                float4 w1 = *(const float4*)&sW1[c + 32][k0];
                float4 w2 = *(const float4*)&sW1[c + 64][k0];
                #pragma unroll
                for (int i = 0; i < 4; ++i) {
                    float4 av = *(const float4*)&sea[g * 4 + i][k0];
                    hacc[i][0] = fmaf(av.w, w0.w, fmaf(av.z, w0.z, fmaf(av.y, w0.y, fmaf(av.x, w0.x, hacc[i][0]))));
                    hacc[i][1] = fmaf(av.w, w1.w, fmaf(av.z, w1.z, fmaf(av.y, w1.y, fmaf(av.x, w1.x, hacc[i][1]))));
                    hacc[i][2] = fmaf(av.w, w2.w, fmaf(av.z, w2.z, fmaf(av.y, w2.y, fmaf(av.x, w2.x, hacc[i][2]))));
                }
            }
            #pragma unroll
            for (int i = 0; i < 4; ++i) {
                int e = g * 4 + i;
                #pragma unroll
                for (int j = 0; j < 3; ++j) {
                    int d = c + 32 * j;
                    float v = fmaxf(hacc[i][j], 0.f);
                    unsigned short hb = f2bf(v);
                    sh_hi[e][d] = hb;
                    sh_lo[e][d] = f2bf(v - bf2f(hb));
                }
            }
        }
        __syncthreads();

        // ---- w = h @ W2^T via MFMA split-3 ----
        f32x4 acc[3];
        #pragma unroll
        for (int t = 0; t < 3; ++t) acc[t] = (f32x4){0.f, 0.f, 0.f, 0.f};

        const int arow = mr * 16 + l15;
        #pragma unroll
        for (int chunk = 0; chunk < 3; ++chunk) {
            const int koff = chunk * 32 + l4 * 8;
            s16x8 a_hi = *(const s16x8*)&sh_hi[arow][koff];
            s16x8 a_lo = *(const s16x8*)&sh_lo[arow][koff];
            #pragma unroll
            for (int t = 0; t < 3; ++t) {
                const int brow = (ng * 3 + t) * 16 + l15;
                s16x8 b_hi = *(const s16x8*)&sW2h[brow][koff];
                s16x8 b_lo = *(const s16x8*)&sW2l[brow][koff];
                acc[t] = __builtin_amdgcn_mfma_f32_16x16x32_bf16(a_hi, b_hi, acc[t], 0, 0, 0);
                acc[t] = __builtin_amdgcn_mfma_f32_16x16x32_bf16(a_hi, b_lo, acc[t], 0, 0, 0);
                acc[t] = __builtin_amdgcn_mfma_f32_16x16x32_bf16(a_lo, b_hi, acc[t], 0, 0, 0);
            }
        }

        // ---- epilogue: bias + gather x[src] + atomic scatter to agg[dst] ----
        // D layout: col = lane&15 (d), row = (lane>>4)*4 + j (edge) [m89-verified]
        #pragma unroll
        for (int t = 0; t < 3; ++t) {
            const int d = (ng * 3 + t) * 16 + l15;
            #pragma unroll
            for (int j = 0; j < 4; ++j) {
                const int el = mr * 16 + l4 * 4 + j;
                const int e  = e0 + el;
                if (e < E) {
                    float wval = acc[t][j] + bias[t];
                    int s = ssrc[el], dn = sdst[el];
                    atomicAdd(&agg[(size_t)dn * 96 + d], wval * x[(size_t)s * 96 + d]);
                }
            }
        }
    }
}

// ---------------------------------------------------------------------------
// Kernel 2: out = relu(x @ Ws^T + bs + agg @ Wn^T + bn)  (unchanged)
// ---------------------------------------------------------------------------
__global__ __launch_bounds__(BLOCK, 4) void node_kernel(
    const float* __restrict__ x,
    const float* __restrict__ agg,
    const float* __restrict__ Ws, const float* __restrict__ bs,
    const float* __restrict__ Wn, const float* __restrict__ bn,
    float* __restrict__ out, int N)
{
    __shared__ float sW[96][100];
    __shared__ float sxa[TN][100];
    __shared__ float sbias[96];

    const int tid = threadIdx.x;
    const int c = tid & 31, g = tid >> 5;
    const int n0 = blockIdx.x * TN;

    if (tid < 96) sbias[tid] = bs[tid] + bn[tid];

    float acc[4][3];
    #pragma unroll
    for (int i = 0; i < 4; ++i)
        for (int j = 0; j < 3; ++j) acc[i][j] = 0.f;

    for (int ph = 0; ph < 2; ++ph) {
        const float* __restrict__ W   = ph ? Wn : Ws;
        const float* __restrict__ src = ph ? agg : x;
        __syncthreads();
        for (int idx = tid; idx < 96 * 24; idx += BLOCK) {
            int d = idx / 24, kq = idx - d * 24;
            *(float4*)&sW[d][kq * 4] = *(const float4*)&W[d * 96 + kq * 4];
        }
        for (int idx = tid; idx < TN * 24; idx += BLOCK) {
            int n = idx / 24, kq = idx - n * 24;
            float4 v = make_float4(0.f, 0.f, 0.f, 0.f);
            if (n0 + n < N) v = *(const float4*)&src[(size_t)(n0 + n) * 96 + kq * 4];
            *(float4*)&sxa[n][kq * 4] = v;
        }
        __syncthreads();
        #pragma unroll 2
        for (int k0 = 0; k0 < 96; k0 += 4) {
            float4 w0 = *(const float4*)&sW[c][k0];
            float4 w1 = *(const float4*)&sW[c + 32][k0];
            float4 w2 = *(const float4*)&sW[c + 64][k0];
            #pragma unroll
            for (int i = 0; i < 4; ++i) {
                float4 xv = *(const float4*)&sxa[g * 4 + i][k0];
                acc[i][0] = fmaf(xv.w, w0.w, fmaf(xv.z, w0.z, fmaf(xv.y, w0.y, fmaf(xv.x, w0.x, acc[i][0]))));
                acc[i][1] = fmaf(xv.w, w1.w, fmaf(xv.z, w1.z, fmaf(xv.y, w1.y, fmaf(xv.x, w1.x, acc[i][1]))));
                acc[i][2] = fmaf(xv.w, w2.w, fmaf(xv.z, w2.z, fmaf(xv.y, w2.y, fmaf(xv.x, w2.x, acc[i][2]))));
            }
        }
    }

    #pragma unroll
    for (int i = 0; i < 4; ++i) {
        int n = n0 + g * 4 + i;
        if (n < N) {
            out[(size_t)n * 96 + c]      = fmaxf(acc[i][0] + sbias[c], 0.f);
            out[(size_t)n * 96 + c + 32] = fmaxf(acc[i][1] + sbias[c + 32], 0.f);
            out[(size_t)n * 96 + c + 64] = fmaxf(acc[i][2] + sbias[c + 64], 0.f);
        }
    }
}

extern "C" void kernel_launch(void* const* d_in, const int* in_sizes, int n_in,
                              void* d_out, int out_size, void* d_ws, size_t ws_size,
                              hipStream_t stream) {
    const float* x  = (const float*)d_in[0];
    const int*   ei = (const int*)d_in[1];
    const float* ea = (const float*)d_in[2];
    const float* W1 = (const float*)d_in[3];
    const float* b1 = (const float*)d_in[4];
    const float* W2 = (const float*)d_in[5];
    const float* b2 = (const float*)d_in[6];
    const float* Ws = (const float*)d_in[7];
    const float* bs = (const float*)d_in[8];
    const float* Wn = (const float*)d_in[9];
    const float* bn = (const float*)d_in[10];
    float* out = (float*)d_out;

    const int N = in_sizes[0] / 96;
    const int E = in_sizes[2] / 17;

    float* agg = (ws_size >= (size_t)N * 96 * sizeof(float)) ? (float*)d_ws : out;
    hipMemsetAsync(agg, 0, (size_t)N * 96 * sizeof(float), stream);

    edge_kernel<<<512, BLOCK, 0, stream>>>(x, ei, ea, W1, b1, W2, b2, agg, N, E);
    node_kernel<<<(N + TN - 1) / TN, BLOCK, 0, stream>>>(x, agg, Ws, bs, Wn, bn, out, N);
}

// Round 4
// 319.422 us; speedup vs baseline: 1.9853x; 1.0719x over previous
//
#include <hip/hip_runtime.h>

#define BLOCK 512
#define TE 64   // edges per tile
#define TN 64   // nodes per tile
#define NTB 512 // edge grid blocks (2 per CU)

typedef float f32x4 __attribute__((ext_vector_type(4)));
typedef short s16x8 __attribute__((ext_vector_type(8)));

static __device__ __forceinline__ unsigned short f2bf(float f) {
    unsigned int u = __float_as_uint(f);
    u += 0x7FFFu + ((u >> 16) & 1u);          // round-to-nearest-even
    return (unsigned short)(u >> 16);
}
static __device__ __forceinline__ float bf2f(unsigned short s) {
    return __uint_as_float(((unsigned int)s) << 16);
}

// ---------------------------------------------------------------------------
// Edge kernel, software-pipelined:
//  A: atomics(t-1) | prefetch ea/idx(t+1)->regs | gather x(t)->regs | h(t)
//  BAR1
//  B: MFMA(t) | LDS-stage(t+1) from regs | wvx=(acc+bias)*x -> carry regs
//  BAR2
// W2 in fragment-linear LDS (lane-linear 16B reads). sh chunk-major [3][64][40].
// LDS ~79.4KB -> 2 blocks/CU.
// ---------------------------------------------------------------------------
__global__ __launch_bounds__(BLOCK, 4) void edge_kernel(
    const float* __restrict__ x,     // [N][96]
    const int*   __restrict__ ei,    // [2][E]
    const float* __restrict__ ea,    // [E][17]
    const float* __restrict__ W1,    // [96][17]
    const float* __restrict__ b1,    // [96]
    const float* __restrict__ W2,    // [96][96]
    const float* __restrict__ b2,    // [96]
    float* __restrict__ agg,         // [N][96]
    int N, int E)
{
    __shared__ unsigned short sBh[9216];      // W2 hi, fragment-linear
    __shared__ unsigned short sBl[9216];      // W2 lo
    __shared__ unsigned short sAh[3][TE][40]; // h hi, chunk-major, 16B-aligned rows
    __shared__ unsigned short sAl[3][TE][40]; // h lo
    __shared__ float sW1[96][20];
    __shared__ float sea[TE][20];
    __shared__ float sb1[96];
    __shared__ int   ssrc[TE], sdst[TE];

    const int tid  = threadIdx.x;
    const int c    = tid & 31;         // h-phase d-lane
    const int g    = tid >> 5;         // h-phase edge group
    const int lane = tid & 63;
    const int wv   = tid >> 6;         // wave 0..7
    const int mr   = wv & 3;           // m-row (16 edges)
    const int ng   = wv >> 2;          // n-half
    const int l15  = lane & 15;
    const int l4   = lane >> 4;

    const int ntiles = (E + TE - 1) / TE;

    // ---- prefetch tile0 into regs (flies under weight staging) ----
    const int pe = tid >> 3, ps = tid & 7;
    float pf0 = 0.f, pf1 = 0.f, pf2 = 0.f; int pidx = 0;
    int tile = blockIdx.x;
    {
        int e0n = tile * TE;
        int ee  = e0n + pe; if (ee >= E) ee = E - 1;
        const float* er = ea + (size_t)ee * 17;
        pf0 = er[ps];
        pf1 = er[ps + 8];
        if (ps == 0) pf2 = er[16];
        if (tid < TE)            { int e = e0n + tid;      pidx = (e < E) ? ei[e]     : 0; }
        else if (tid < 2 * TE)   { int e = e0n + tid - TE; pidx = (e < E) ? ei[E + e] : 0; }
    }

    // ---- one-time staging ----
    for (int idx = tid; idx < 96 * 20; idx += BLOCK) {
        int d = idx / 20, k = idx - d * 20;
        sW1[d][k] = (k < 17) ? W1[d * 17 + k] : 0.f;
    }
    for (int idx = tid; idx < 96 * 96; idx += BLOCK) {
        int d = idx / 96, k = idx - d * 96;
        float v = W2[idx];
        unsigned short hb = f2bf(v);
        int ngf = d / 48, tt = (d % 48) / 16, r = d & 15;
        int ch = k >> 5, kl4 = (k & 31) >> 3, sb = k & 7;
        int fo = ((((ngf * 3 + tt) * 3 + ch) * 4 + kl4) * 16 + r) * 8 + sb;
        sBh[fo] = hb;
        sBl[fo] = f2bf(v - bf2f(hb));
    }
    if (tid < 96) sb1[tid] = b1[tid];
    if (tid < TE) { sea[tid][17] = 0.f; sea[tid][18] = 0.f; sea[tid][19] = 0.f; }

    float bias[3]; int dv[3];
    #pragma unroll
    for (int t = 0; t < 3; ++t) {
        dv[t]   = (ng * 3 + t) * 16 + l15;
        bias[t] = b2[dv[t]];
    }

    __syncthreads();   // weights staged, tile0 prefetch drained

    // write tile0 stage
    sea[pe][ps]     = pf0;
    sea[pe][ps + 8] = pf1;
    if (ps == 0) sea[pe][16] = pf2;
    if (tid < TE)          ssrc[tid]      = pidx;
    else if (tid < 2 * TE) sdst[tid - TE] = pidx;
    __syncthreads();

    float p_wvx[12]; int p_dn[4]; int p_e0 = 0;
    const int first = blockIdx.x;

    for (; tile < ntiles; tile += NTB) {
        const int nxt = tile + NTB;

        // ================= Phase A =================
        // (1) previous tile's atomics — fly under h-compute
        if (tile != first) {
            #pragma unroll
            for (int t = 0; t < 3; ++t)
                #pragma unroll
                for (int j = 0; j < 4; ++j) {
                    int e = p_e0 + mr * 16 + l4 * 4 + j;
                    if (e < E)
                        atomicAdd(&agg[(size_t)p_dn[j] * 96 + dv[t]], p_wvx[t * 4 + j]);
                }
        }

        // (2) prefetch tile t+1 ea/idx into regs
        if (nxt < ntiles) {
            int e0n = nxt * TE;
            int ee  = e0n + pe; if (ee >= E) ee = E - 1;
            const float* er = ea + (size_t)ee * 17;
            pf0 = er[ps];
            pf1 = er[ps + 8];
            if (ps == 0) pf2 = er[16];
            if (tid < TE)            { int e = e0n + tid;      pidx = (e < E) ? ei[e]     : 0; }
            else if (tid < 2 * TE)   { int e = e0n + tid - TE; pidx = (e < E) ? ei[E + e] : 0; }
        }

        // (3) gather x[src] for tile t into regs; read dst while valid
        int sg[4], ndn[4];
        #pragma unroll
        for (int j = 0; j < 4; ++j) {
            int elj = mr * 16 + l4 * 4 + j;
            sg[j]  = ssrc[elj];
            ndn[j] = sdst[elj];
        }
        float xg[12];
        #pragma unroll
        for (int t = 0; t < 3; ++t)
            #pragma unroll
            for (int j = 0; j < 4; ++j)
                xg[t * 4 + j] = x[(size_t)sg[j] * 96 + dv[t]];

        // (4) h = relu(ea @ W1^T + b1) -> bf16 hi/lo into sA (chunk-major)
        {
            float hacc[4][3];
            #pragma unroll
            for (int i = 0; i < 4; ++i) {
                hacc[i][0] = sb1[c]; hacc[i][1] = sb1[c + 32]; hacc[i][2] = sb1[c + 64];
            }
            #pragma unroll
            for (int k0 = 0; k0 < 20; k0 += 4) {
                float4 w0 = *(const float4*)&sW1[c][k0];
                float4 w1 = *(const float4*)&sW1[c + 32][k0];
                float4 w2 = *(const float4*)&sW1[c + 64][k0];
                #pragma unroll
                for (int i = 0; i < 4; ++i) {
                    float4 av = *(const float4*)&sea[g * 4 + i][k0];
                    hacc[i][0] = fmaf(av.w, w0.w, fmaf(av.z, w0.z, fmaf(av.y, w0.y, fmaf(av.x, w0.x, hacc[i][0]))));
                    hacc[i][1] = fmaf(av.w, w1.w, fmaf(av.z, w1.z, fmaf(av.y, w1.y, fmaf(av.x, w1.x, hacc[i][1]))));
                    hacc[i][2] = fmaf(av.w, w2.w, fmaf(av.z, w2.z, fmaf(av.y, w2.y, fmaf(av.x, w2.x, hacc[i][2]))));
                }
            }
            #pragma unroll
            for (int i = 0; i < 4; ++i) {
                int e = g * 4 + i;
                #pragma unroll
                for (int j = 0; j < 3; ++j) {
                    float v = fmaxf(hacc[i][j], 0.f);
                    unsigned short hb = f2bf(v);
                    sAh[j][e][c] = hb;
                    sAl[j][e][c] = f2bf(v - bf2f(hb));
                }
            }
        }
        __syncthreads();   // BAR1: sA visible; vm queue (atomics/gathers/prefetch) drained after full h-phase

        // ================= Phase B =================
        // MFMA split-3
        f32x4 acc[3];
        #pragma unroll
        for (int t = 0; t < 3; ++t) acc[t] = (f32x4){0.f, 0.f, 0.f, 0.f};
        const int arow = mr * 16 + l15;
        #pragma unroll
        for (int chunk = 0; chunk < 3; ++chunk) {
            s16x8 a_hi = *(const s16x8*)&sAh[chunk][arow][l4 * 8];
            s16x8 a_lo = *(const s16x8*)&sAl[chunk][arow][l4 * 8];
            #pragma unroll
            for (int t = 0; t < 3; ++t) {
                const int base = (((ng * 3 + t) * 3 + chunk) * 64 + lane) * 8;
                s16x8 b_hi = *(const s16x8*)&sBh[base];
                s16x8 b_lo = *(const s16x8*)&sBl[base];
                acc[t] = __builtin_amdgcn_mfma_f32_16x16x32_bf16(a_hi, b_hi, acc[t], 0, 0, 0);
                acc[t] = __builtin_amdgcn_mfma_f32_16x16x32_bf16(a_hi, b_lo, acc[t], 0, 0, 0);
                acc[t] = __builtin_amdgcn_mfma_f32_16x16x32_bf16(a_lo, b_hi, acc[t], 0, 0, 0);
            }
        }

        // stage tile t+1 into LDS from prefetch regs (sea/ssrc/sdst not read in B)
        if (nxt < ntiles) {
            sea[pe][ps]     = pf0;
            sea[pe][ps + 8] = pf1;
            if (ps == 0) sea[pe][16] = pf2;
            if (tid < TE)          ssrc[tid]      = pidx;
            else if (tid < 2 * TE) sdst[tid - TE] = pidx;
        }

        // epilogue values -> carry regs (gathers already drained at BAR1)
        #pragma unroll
        for (int t = 0; t < 3; ++t)
            #pragma unroll
            for (int j = 0; j < 4; ++j)
                p_wvx[t * 4 + j] = (acc[t][j] + bias[t]) * xg[t * 4 + j];
        #pragma unroll
        for (int j = 0; j < 4; ++j) p_dn[j] = ndn[j];
        p_e0 = tile * TE;

        __syncthreads();   // BAR2: tile t+1 stage visible; sA consumed
    }

    // tail: last tile's atomics
    if (first < ntiles) {
        #pragma unroll
        for (int t = 0; t < 3; ++t)
            #pragma unroll
            for (int j = 0; j < 4; ++j) {
                int e = p_e0 + mr * 16 + l4 * 4 + j;
                if (e < E)
                    atomicAdd(&agg[(size_t)p_dn[j] * 96 + dv[t]], p_wvx[t * 4 + j]);
            }
    }
}

// ---------------------------------------------------------------------------
// Kernel 2: out = relu(x @ Ws^T + bs + agg @ Wn^T + bn)  (unchanged)
// ---------------------------------------------------------------------------
__global__ __launch_bounds__(BLOCK, 4) void node_kernel(
    const float* __restrict__ x,
    const float* __restrict__ agg,
    const float* __restrict__ Ws, const float* __restrict__ bs,
    const float* __restrict__ Wn, const float* __restrict__ bn,
    float* __restrict__ out, int N)
{
    __shared__ float sW[96][100];
    __shared__ float sxa[TN][100];
    __shared__ float sbias[96];

    const int tid = threadIdx.x;
    const int c = tid & 31, g = tid >> 5;
    const int n0 = blockIdx.x * TN;

    if (tid < 96) sbias[tid] = bs[tid] + bn[tid];

    float acc[4][3];
    #pragma unroll
    for (int i = 0; i < 4; ++i)
        for (int j = 0; j < 3; ++j) acc[i][j] = 0.f;

    for (int ph = 0; ph < 2; ++ph) {
        const float* __restrict__ W   = ph ? Wn : Ws;
        const float* __restrict__ src = ph ? agg : x;
        __syncthreads();
        for (int idx = tid; idx < 96 * 24; idx += BLOCK) {
            int d = idx / 24, kq = idx - d * 24;
            *(float4*)&sW[d][kq * 4] = *(const float4*)&W[d * 96 + kq * 4];
        }
        for (int idx = tid; idx < TN * 24; idx += BLOCK) {
            int n = idx / 24, kq = idx - n * 24;
            float4 v = make_float4(0.f, 0.f, 0.f, 0.f);
            if (n0 + n < N) v = *(const float4*)&src[(size_t)(n0 + n) * 96 + kq * 4];
            *(float4*)&sxa[n][kq * 4] = v;
        }
        __syncthreads();
        #pragma unroll 2
        for (int k0 = 0; k0 < 96; k0 += 4) {
            float4 w0 = *(const float4*)&sW[c][k0];
            float4 w1 = *(const float4*)&sW[c + 32][k0];
            float4 w2 = *(const float4*)&sW[c + 64][k0];
            #pragma unroll
            for (int i = 0; i < 4; ++i) {
                float4 xv = *(const float4*)&sxa[g * 4 + i][k0];
                acc[i][0] = fmaf(xv.w, w0.w, fmaf(xv.z, w0.z, fmaf(xv.y, w0.y, fmaf(xv.x, w0.x, acc[i][0]))));
                acc[i][1] = fmaf(xv.w, w1.w, fmaf(xv.z, w1.z, fmaf(xv.y, w1.y, fmaf(xv.x, w1.x, acc[i][1]))));
                acc[i][2] = fmaf(xv.w, w2.w, fmaf(xv.z, w2.z, fmaf(xv.y, w2.y, fmaf(xv.x, w2.x, acc[i][2]))));
            }
        }
    }

    #pragma unroll
    for (int i = 0; i < 4; ++i) {
        int n = n0 + g * 4 + i;
        if (n < N) {
            out[(size_t)n * 96 + c]      = fmaxf(acc[i][0] + sbias[c], 0.f);
            out[(size_t)n * 96 + c + 32] = fmaxf(acc[i][1] + sbias[c + 32], 0.f);
            out[(size_t)n * 96 + c + 64] = fmaxf(acc[i][2] + sbias[c + 64], 0.f);
        }
    }
}

extern "C" void kernel_launch(void* const* d_in, const int* in_sizes, int n_in,
                              void* d_out, int out_size, void* d_ws, size_t ws_size,
                              hipStream_t stream) {
    const float* x  = (const float*)d_in[0];
    const int*   ei = (const int*)d_in[1];
    const float* ea = (const float*)d_in[2];
    const float* W1 = (const float*)d_in[3];
    const float* b1 = (const float*)d_in[4];
    const float* W2 = (const float*)d_in[5];
    const float* b2 = (const float*)d_in[6];
    const float* Ws = (const float*)d_in[7];
    const float* bs = (const float*)d_in[8];
    const float* Wn = (const float*)d_in[9];
    const float* bn = (const float*)d_in[10];
    float* out = (float*)d_out;

    const int N = in_sizes[0] / 96;
    const int E = in_sizes[2] / 17;

    float* agg = (ws_size >= (size_t)N * 96 * sizeof(float)) ? (float*)d_ws : out;
    hipMemsetAsync(agg, 0, (size_t)N * 96 * sizeof(float), stream);

    edge_kernel<<<NTB, BLOCK, 0, stream>>>(x, ei, ea, W1, b1, W2, b2, agg, N, E);
    node_kernel<<<(N + TN - 1) / TN, BLOCK, 0, stream>>>(x, agg, Ws, bs, Wn, bn, out, N);
}